// Round 4
// baseline (911.313 us; speedup 1.0000x reference)
//
#include <hip/hip_runtime.h>
#include <math.h>

#define N_TOK 128
#define ADIM  256
#define EDIM  512
#define BSZ   8
#define NSQ   65536

typedef short bf16x8 __attribute__((ext_vector_type(8)));
typedef float f32x4  __attribute__((ext_vector_type(4)));
#define MFMA_BF16(a, b, c) __builtin_amdgcn_mfma_f32_16x16x32_bf16((a), (b), (c), 0, 0, 0)

__device__ inline short f2bf(float f) {   // RNE float -> bf16
  union { float f; unsigned u; } v; v.f = f;
  unsigned r = v.u + 0x7fff + ((v.u >> 16) & 1);
  return (short)(r >> 16);
}

// async global->LDS, 16B per lane. LDS dest is wave-uniform base + lane*16.
typedef const __attribute__((address_space(1))) unsigned int* gas_ptr;
typedef __attribute__((address_space(3))) unsigned int* las_ptr;
__device__ __forceinline__ void gload16(const void* g, void* l) {
  __builtin_amdgcn_global_load_lds((gas_ptr)g, (las_ptr)l, 16, 0, 0);
}

struct ProjArgs {
  const float* W[7];
  const float* b[7];
};

// ---------------- projections: proj[p][b*128+i][a] = elu(h @ W_p + b_p), bf16
__global__ __launch_bounds__(256) void proj_kernel(
    const float* __restrict__ x, const float* __restrict__ sentinel,
    ProjArgs args, short* __restrict__ proj)
{
  const int p  = blockIdx.y;
  const int m0 = blockIdx.x * 8;
  const int tid = threadIdx.x;
  __shared__ float hs[8][EDIM];
  #pragma unroll
  for (int q = 0; q < 16; ++q) {
    int idx = tid + q * 256;
    int r = idx >> 9, c = idx & 511;
    int m = m0 + r, b = m >> 7, i = m & 127;
    hs[r][c] = (i == 0) ? sentinel[c] : x[((size_t)(b * 127) + (i - 1)) * EDIM + c];
  }
  __syncthreads();
  const float* W = args.W[p];
  float bias = args.b[p][tid];
  float acc[8];
  #pragma unroll
  for (int r = 0; r < 8; ++r) acc[r] = bias;
  #pragma unroll 4
  for (int k = 0; k < EDIM; ++k) {
    float wv = W[(size_t)k * ADIM + tid];
    #pragma unroll
    for (int r = 0; r < 8; ++r) acc[r] = fmaf(hs[r][k], wv, acc[r]);
  }
  short* outp = proj + ((size_t)p * (BSZ * N_TOK) + m0) * ADIM + tid;
  #pragma unroll
  for (int r = 0; r < 8; ++r) {
    float v = acc[r];
    v = v > 0.f ? v : expm1f(v);
    outp[(size_t)r * ADIM] = f2bf(v);
  }
}

// ---------------- U permute+convert: Ut[(d*256+c)][a] = bf16(U[a][c*256+d]) --
__global__ __launch_bounds__(256) void permU(
    const float* __restrict__ U, short* __restrict__ Ut)
{
  __shared__ float tile[64][69];
  const int c  = blockIdx.x;
  const int a0 = blockIdx.y * 64;
  const int d0 = blockIdx.z * 64;
  const int t  = threadIdx.x;
  {
    int ar = t >> 4, ds4 = (t & 15) * 4;
    #pragma unroll
    for (int q = 0; q < 4; ++q) {
      int a = ar + q * 16;
      float4 v = *(const float4*)&U[(size_t)(a0 + a) * NSQ + c * 256 + d0 + ds4];
      tile[a][ds4] = v.x; tile[a][ds4 + 1] = v.y;
      tile[a][ds4 + 2] = v.z; tile[a][ds4 + 3] = v.w;
    }
  }
  __syncthreads();
  {
    int dr = t >> 4, as4 = (t & 15) * 4;
    #pragma unroll
    for (int q = 0; q < 4; ++q) {
      int d = dr + q * 16;
      ushort4 o;
      o.x = (unsigned short)f2bf(tile[as4 + 0][d]);
      o.y = (unsigned short)f2bf(tile[as4 + 1][d]);
      o.z = (unsigned short)f2bf(tile[as4 + 2][d]);
      o.w = (unsigned short)f2bf(tile[as4 + 3][d]);
      *(ushort4*)&Ut[((size_t)(d0 + d) * 256 + c) * 256 + a0 + as4] = o;
    }
  }
}

// ======== shared GEMM structure =============================================
// LDS tiles: unpadded [128][32] bf16, double-buffered. Staged linearly by
// global_load_lds from a PRE-SWIZZLED global source; ds_read uses the same
// XOR: slot' = slot ^ ((row>>1)&3) -> conflict-free b128 reads.
// 2-phase pipeline: issue stage(kt+1) BEFORE compute(kt); one barrier/K-step
// (its implicit vmcnt(0) covers the in-flight global_load_lds).

// ---------------- t1[bi][d*256+c] = sum_a uproj[bi][a] * Ut[d*256+c][a] -----
// M=1024, N=65536, K=256. 128x128 tile, 4 waves, swapped-MFMA packed epilogue.
__global__ __launch_bounds__(256) void gemm_t1(
    const short* __restrict__ A,    // [1024][256] bf16 (u-projection)
    const short* __restrict__ Ut,   // [65536][256] bf16 (B^T layout)
    short* __restrict__ C)          // [1024][65536] bf16
{
  __shared__ short As[2][128 * 32];
  __shared__ short Bs[2][128 * 32];
  const int tid = threadIdx.x;
  const int wave = tid >> 6, lane = tid & 63;
  const int ln15 = lane & 15, quad = lane >> 4;
  const int m0 = blockIdx.x * 128, n0 = blockIdx.y * 128;
  const int wm = (wave & 1) * 64, wn = (wave >> 1) * 64;
  const int q0 = tid,        r0 = q0 >> 2, s0 = (q0 & 3) ^ ((r0 >> 1) & 3);
  const int q1 = tid + 256,  r1 = q1 >> 2, s1 = (q1 & 3) ^ ((r1 >> 1) & 3);
  const int rdoff = ((quad ^ ((ln15 >> 1) & 3)) << 3);
  const short* gA0 = &A [(size_t)(m0 + r0) * ADIM + s0 * 8];
  const short* gA1 = &A [(size_t)(m0 + r1) * ADIM + s1 * 8];
  const short* gB0 = &Ut[(size_t)(n0 + r0) * ADIM + s0 * 8];
  const short* gB1 = &Ut[(size_t)(n0 + r1) * ADIM + s1 * 8];
  f32x4 acc[4][4] = {};
  // prologue: stage kt=0 into buffer 0
  gload16(gA0, &As[0][q0 * 8]);
  gload16(gA1, &As[0][q1 * 8]);
  gload16(gB0, &Bs[0][q0 * 8]);
  gload16(gB1, &Bs[0][q1 * 8]);
  __syncthreads();
  int cur = 0;
  for (int kt = 0; kt < ADIM; kt += 32) {
    if (kt + 32 < ADIM) {               // stage next tile into cur^1
      gload16(gA0 + kt + 32, &As[cur ^ 1][q0 * 8]);
      gload16(gA1 + kt + 32, &As[cur ^ 1][q1 * 8]);
      gload16(gB0 + kt + 32, &Bs[cur ^ 1][q0 * 8]);
      gload16(gB1 + kt + 32, &Bs[cur ^ 1][q1 * 8]);
    }
    bf16x8 af[4], bfr[4];
    #pragma unroll
    for (int r = 0; r < 4; ++r)
      af[r]  = *(bf16x8*)&As[cur][(wm + r * 16 + ln15) * 32 + rdoff];
    #pragma unroll
    for (int c2 = 0; c2 < 4; ++c2)
      bfr[c2] = *(bf16x8*)&Bs[cur][(wn + c2 * 16 + ln15) * 32 + rdoff];
    #pragma unroll
    for (int r = 0; r < 4; ++r)
      #pragma unroll
      for (int c2 = 0; c2 < 4; ++c2)
        acc[r][c2] = MFMA_BF16(bfr[c2], af[r], acc[r][c2]);  // swapped: lane holds 4 consecutive n
    __syncthreads();                    // drains vmcnt(0): next buffer ready
    cur ^= 1;
  }
  #pragma unroll
  for (int r = 0; r < 4; ++r)
    #pragma unroll
    for (int c2 = 0; c2 < 4; ++c2) {
      int m = m0 + wm + r * 16 + ln15;
      int n = n0 + wn + c2 * 16 + quad * 4;
      ushort4 o;
      o.x = (unsigned short)f2bf(acc[r][c2][0]);
      o.y = (unsigned short)f2bf(acc[r][c2][1]);
      o.z = (unsigned short)f2bf(acc[r][c2][2]);
      o.w = (unsigned short)f2bf(acc[r][c2][3]);
      *(ushort4*)&C[(size_t)m * NSQ + n] = o;
    }
}

// ---------------- phase A (per b): t2[b][i][j][d] = sum_c v[b,j,c]*t1[b,i,c,d]
// A = projv[b] [128(j) x 256(c)]; B^T = t1[b] rows n'=(i*256+d), stride 256.
// M=128, N=32768, K=256.  grid = (256 n-tiles, 8)
__global__ __launch_bounds__(256) void gemm_t2(
    const short* __restrict__ t1,     // [1024][65536] bf16
    const short* __restrict__ projv,  // [1024][256] bf16
    short* __restrict__ t2)           // [8][128(i)][128(j)][256(d)] bf16
{
  __shared__ short As[2][128 * 32];
  __shared__ short Bs[2][128 * 32];
  const int tid = threadIdx.x;
  const int wave = tid >> 6, lane = tid & 63;
  const int ln15 = lane & 15, quad = lane >> 4;
  const int n0 = blockIdx.x * 128;
  const int bl = blockIdx.y;
  const short* Bt = t1 + (size_t)bl * N_TOK * NSQ;      // rows n'=(i,d), stride 256
  const short* Av = projv + (size_t)bl * N_TOK * ADIM;  // rows j, stride 256
  const int wm = (wave & 1) * 64, wn = (wave >> 1) * 64;
  const int q0 = tid,        r0 = q0 >> 2, s0 = (q0 & 3) ^ ((r0 >> 1) & 3);
  const int q1 = tid + 256,  r1 = q1 >> 2, s1 = (q1 & 3) ^ ((r1 >> 1) & 3);
  const int rdoff = ((quad ^ ((ln15 >> 1) & 3)) << 3);
  const short* gA0 = &Av[(size_t)r0 * ADIM + s0 * 8];
  const short* gA1 = &Av[(size_t)r1 * ADIM + s1 * 8];
  const short* gB0 = &Bt[(size_t)(n0 + r0) * ADIM + s0 * 8];
  const short* gB1 = &Bt[(size_t)(n0 + r1) * ADIM + s1 * 8];
  f32x4 acc[4][4] = {};
  gload16(gA0, &As[0][q0 * 8]);
  gload16(gA1, &As[0][q1 * 8]);
  gload16(gB0, &Bs[0][q0 * 8]);
  gload16(gB1, &Bs[0][q1 * 8]);
  __syncthreads();
  int cur = 0;
  for (int kt = 0; kt < ADIM; kt += 32) {
    if (kt + 32 < ADIM) {
      gload16(gA0 + kt + 32, &As[cur ^ 1][q0 * 8]);
      gload16(gA1 + kt + 32, &As[cur ^ 1][q1 * 8]);
      gload16(gB0 + kt + 32, &Bs[cur ^ 1][q0 * 8]);
      gload16(gB1 + kt + 32, &Bs[cur ^ 1][q1 * 8]);
    }
    bf16x8 af[4], bfr[4];
    #pragma unroll
    for (int r = 0; r < 4; ++r)
      af[r]  = *(bf16x8*)&As[cur][(wm + r * 16 + ln15) * 32 + rdoff];
    #pragma unroll
    for (int c2 = 0; c2 < 4; ++c2)
      bfr[c2] = *(bf16x8*)&Bs[cur][(wn + c2 * 16 + ln15) * 32 + rdoff];
    #pragma unroll
    for (int r = 0; r < 4; ++r)
      #pragma unroll
      for (int c2 = 0; c2 < 4; ++c2)
        acc[r][c2] = MFMA_BF16(bfr[c2], af[r], acc[r][c2]);
    __syncthreads();
    cur ^= 1;
  }
  // n-tile (128-aligned) covers single i, d in [dbase, dbase+128)
  const int i     = n0 >> 8;
  const int dbase = n0 & 255;
  short* ob = t2 + (size_t)bl * (N_TOK * N_TOK * ADIM) + (size_t)i * (N_TOK * ADIM);
  #pragma unroll
  for (int r = 0; r < 4; ++r)
    #pragma unroll
    for (int c2 = 0; c2 < 4; ++c2) {
      int j = wm + r * 16 + ln15;
      int d = dbase + wn + c2 * 16 + quad * 4;
      ushort4 o;
      o.x = (unsigned short)f2bf(acc[r][c2][0]);
      o.y = (unsigned short)f2bf(acc[r][c2][1]);
      o.z = (unsigned short)f2bf(acc[r][c2][2]);
      o.w = (unsigned short)f2bf(acc[r][c2][3]);
      *(ushort4*)&ob[(size_t)j * ADIM + d] = o;
    }
}

// ---------------- phase B (per b): S[b][i][j][k] = sum_d t2[b,i,j,d]*w[b,k,d]
// M=16384 (i,j), N=128 (k), K=256. Output rows contiguous in final layout.
__global__ __launch_bounds__(256) void gemm_s(
    const short* __restrict__ t2,     // [8][128][128][256] bf16
    const short* __restrict__ projw,  // [1024][256] bf16
    float* __restrict__ out)          // score base for this type [8][128][128][128]
{
  __shared__ short As[2][128 * 32];
  __shared__ short Bs[2][128 * 32];
  const int tid = threadIdx.x;
  const int wave = tid >> 6, lane = tid & 63;
  const int ln15 = lane & 15, quad = lane >> 4;
  const int m0 = blockIdx.x * 128;
  const int bl = blockIdx.y;
  const short* At = t2 + (size_t)bl * (N_TOK * N_TOK * ADIM);  // rows m=(i,j), stride 256
  const short* Bw = projw + (size_t)bl * N_TOK * ADIM;         // rows k, stride 256
  float* ob = out + (size_t)bl * N_TOK * N_TOK * N_TOK + (size_t)m0 * N_TOK;
  const int wm = (wave & 1) * 64, wn = (wave >> 1) * 64;
  const int q0 = tid,        r0 = q0 >> 2, s0 = (q0 & 3) ^ ((r0 >> 1) & 3);
  const int q1 = tid + 256,  r1 = q1 >> 2, s1 = (q1 & 3) ^ ((r1 >> 1) & 3);
  const int rdoff = ((quad ^ ((ln15 >> 1) & 3)) << 3);
  const short* gA0 = &At[(size_t)(m0 + r0) * ADIM + s0 * 8];
  const short* gA1 = &At[(size_t)(m0 + r1) * ADIM + s1 * 8];
  const short* gB0 = &Bw[(size_t)r0 * ADIM + s0 * 8];
  const short* gB1 = &Bw[(size_t)r1 * ADIM + s1 * 8];
  f32x4 acc[4][4] = {};
  gload16(gA0, &As[0][q0 * 8]);
  gload16(gA1, &As[0][q1 * 8]);
  gload16(gB0, &Bs[0][q0 * 8]);
  gload16(gB1, &Bs[0][q1 * 8]);
  __syncthreads();
  int cur = 0;
  for (int kt = 0; kt < ADIM; kt += 32) {
    if (kt + 32 < ADIM) {
      gload16(gA0 + kt + 32, &As[cur ^ 1][q0 * 8]);
      gload16(gA1 + kt + 32, &As[cur ^ 1][q1 * 8]);
      gload16(gB0 + kt + 32, &Bs[cur ^ 1][q0 * 8]);
      gload16(gB1 + kt + 32, &Bs[cur ^ 1][q1 * 8]);
    }
    bf16x8 af[4], bfr[4];
    #pragma unroll
    for (int r = 0; r < 4; ++r)
      af[r]  = *(bf16x8*)&As[cur][(wm + r * 16 + ln15) * 32 + rdoff];
    #pragma unroll
    for (int c2 = 0; c2 < 4; ++c2)
      bfr[c2] = *(bf16x8*)&Bs[cur][(wn + c2 * 16 + ln15) * 32 + rdoff];
    #pragma unroll
    for (int r = 0; r < 4; ++r)
      #pragma unroll
      for (int c2 = 0; c2 < 4; ++c2)
        acc[r][c2] = MFMA_BF16(bfr[c2], af[r], acc[r][c2]);
    __syncthreads();
    cur ^= 1;
  }
  #pragma unroll
  for (int r = 0; r < 4; ++r)
    #pragma unroll
    for (int c2 = 0; c2 < 4; ++c2) {
      int m = wm + r * 16 + ln15;
      int k = wn + c2 * 16 + quad * 4;
      *(f32x4*)&ob[(size_t)m * N_TOK + k] = acc[r][c2];   // 16B store
    }
}

// ---------------- mask passthrough -----------------------------------------
__global__ void mask_kernel(const int* __restrict__ mask, float* __restrict__ out) {
  int idx = blockIdx.x * 256 + threadIdx.x;
  if (idx < BSZ * N_TOK) {
    int b = idx >> 7, i = idx & 127;
    out[idx] = (i == 0) ? 1.0f : (float)mask[b * 127 + i - 1];
  }
}

extern "C" void kernel_launch(void* const* d_in, const int* in_sizes, int n_in,
                              void* d_out, int out_size, void* d_ws, size_t ws_size,
                              hipStream_t stream)
{
  const float* x    = (const float*)d_in[0];
  const int*   mask = (const int*)d_in[2];
  ProjArgs pa;
  for (int p = 0; p < 7; ++p) {
    pa.W[p] = (const float*)d_in[3 + 2 * p];
    pa.b[p] = (const float*)d_in[4 + 2 * p];
  }
  const float* Us[3] = {(const float*)d_in[17], (const float*)d_in[18],
                        (const float*)d_in[19]};
  const float* sentinel = (const float*)d_in[20];

  // workspace: proj 4MB | Ut 32MB | t1 128MB | t2 64MB  (= 228MB, ws is ~786MB)
  short* proj = (short*)d_ws;
  const size_t ut_off = 4u << 20;
  const size_t t1_off = ut_off + ((size_t)NSQ * ADIM * 2);        // +32MB
  const size_t t2_off = t1_off + ((size_t)1024 * NSQ * 2);        // +128MB
  short* Ut = (short*)((char*)d_ws + ut_off);
  short* t1 = (short*)((char*)d_ws + t1_off);
  short* t2 = (short*)((char*)d_ws + t2_off);

  proj_kernel<<<dim3(128, 7), 256, 0, stream>>>(x, sentinel, pa, proj);

  const int u_idx[3] = {0, 2, 4};
  const int v_idx[3] = {1, 3, 6};
  const int w_idx[3] = {1, 2, 5};
  float* outp = (float*)d_out;

  for (int sc = 0; sc < 3; ++sc) {
    permU<<<dim3(256, 4, 4), 256, 0, stream>>>(Us[sc], Ut);
    gemm_t1<<<dim3(8, 512), 256, 0, stream>>>(
        proj + (size_t)u_idx[sc] * 1024 * ADIM, Ut, t1);
    gemm_t2<<<dim3(256, 8), 256, 0, stream>>>(
        t1, proj + (size_t)v_idx[sc] * 1024 * ADIM, t2);
    gemm_s<<<dim3(128, 8), 256, 0, stream>>>(
        t2, proj + (size_t)w_idx[sc] * 1024 * ADIM,
        outp + (size_t)sc * BSZ * N_TOK * N_TOK * N_TOK);
  }
  mask_kernel<<<dim3(4), 256, 0, stream>>>(
      mask, outp + (size_t)3 * BSZ * N_TOK * N_TOK * N_TOK);
}

// Round 5
// 869.789 us; speedup vs baseline: 1.0477x; 1.0477x over previous
//
#include <hip/hip_runtime.h>
#include <math.h>

#define N_TOK 128
#define ADIM  256
#define EDIM  512
#define BSZ   8
#define NSQ   65536

typedef short bf16x8 __attribute__((ext_vector_type(8)));
typedef float f32x4  __attribute__((ext_vector_type(4)));
#define MFMA_BF16(a, b, c) __builtin_amdgcn_mfma_f32_16x16x32_bf16((a), (b), (c), 0, 0, 0)

__device__ inline short f2bf(float f) {   // RNE float -> bf16
  union { float f; unsigned u; } v; v.f = f;
  unsigned r = v.u + 0x7fff + ((v.u >> 16) & 1);
  return (short)(r >> 16);
}

// async global->LDS, 16B per lane. LDS dest is wave-uniform base + lane*16.
typedef const __attribute__((address_space(1))) unsigned int* gas_ptr;
typedef __attribute__((address_space(3))) unsigned int* las_ptr;
__device__ __forceinline__ void gload16(const void* g, void* l) {
  __builtin_amdgcn_global_load_lds((gas_ptr)g, (las_ptr)l, 16, 0, 0);
}

struct ProjArgs {
  const float* W[7];
  const float* b[7];
};
struct UArgs {
  const float* U[3];
};

// ---------------- projections: proj[p][b*128+i][a] = elu(h @ W_p + b_p), bf16
__global__ __launch_bounds__(256) void proj_kernel(
    const float* __restrict__ x, const float* __restrict__ sentinel,
    ProjArgs args, short* __restrict__ proj)
{
  const int p  = blockIdx.y;
  const int m0 = blockIdx.x * 8;
  const int tid = threadIdx.x;
  __shared__ float hs[8][EDIM];
  #pragma unroll
  for (int q = 0; q < 16; ++q) {
    int idx = tid + q * 256;
    int r = idx >> 9, c = idx & 511;
    int m = m0 + r, b = m >> 7, i = m & 127;
    hs[r][c] = (i == 0) ? sentinel[c] : x[((size_t)(b * 127) + (i - 1)) * EDIM + c];
  }
  __syncthreads();
  const float* W = args.W[p];
  float bias = args.b[p][tid];
  float acc[8];
  #pragma unroll
  for (int r = 0; r < 8; ++r) acc[r] = bias;
  #pragma unroll 4
  for (int k = 0; k < EDIM; ++k) {
    float wv = W[(size_t)k * ADIM + tid];
    #pragma unroll
    for (int r = 0; r < 8; ++r) acc[r] = fmaf(hs[r][k], wv, acc[r]);
  }
  short* outp = proj + ((size_t)p * (BSZ * N_TOK) + m0) * ADIM + tid;
  #pragma unroll
  for (int r = 0; r < 8; ++r) {
    float v = acc[r];
    v = v > 0.f ? v : expm1f(v);
    outp[(size_t)r * ADIM] = f2bf(v);
  }
}

// ---------------- U permute+convert, all 3 types in one launch: --------------
// Ut[sc][(d*256+c)][a] = bf16(U_sc[a][c*256+d])
__global__ __launch_bounds__(256) void permU_all(
    UArgs ua, short* __restrict__ UtAll)
{
  __shared__ float tile[64][69];
  const int c  = blockIdx.x;
  const int a0 = blockIdx.y * 64;
  const int z  = blockIdx.z;
  const int sc = z >> 2;
  const int d0 = (z & 3) * 64;
  const float* U = ua.U[sc];
  short* Ut = UtAll + (size_t)sc * NSQ * ADIM;
  const int t  = threadIdx.x;
  {
    int ar = t >> 4, ds4 = (t & 15) * 4;
    #pragma unroll
    for (int q = 0; q < 4; ++q) {
      int a = ar + q * 16;
      float4 v = *(const float4*)&U[(size_t)(a0 + a) * NSQ + c * 256 + d0 + ds4];
      tile[a][ds4] = v.x; tile[a][ds4 + 1] = v.y;
      tile[a][ds4 + 2] = v.z; tile[a][ds4 + 3] = v.w;
    }
  }
  __syncthreads();
  {
    int dr = t >> 4, as4 = (t & 15) * 4;
    #pragma unroll
    for (int q = 0; q < 4; ++q) {
      int d = dr + q * 16;
      ushort4 o;
      o.x = (unsigned short)f2bf(tile[as4 + 0][d]);
      o.y = (unsigned short)f2bf(tile[as4 + 1][d]);
      o.z = (unsigned short)f2bf(tile[as4 + 2][d]);
      o.w = (unsigned short)f2bf(tile[as4 + 3][d]);
      *(ushort4*)&Ut[((size_t)(d0 + d) * 256 + c) * 256 + a0 + as4] = o;
    }
  }
}

// ---------------- t1[bi][d*256+c] = sum_a uproj[bi][a] * Ut[d*256+c][a] -----
// M=1024, N=65536, K=256. 128x128 tile, 4 waves, swapped-MFMA packed epilogue.
// 1D grid with XCD-chunk swizzle: the 8 m-blocks sharing an Ut n-tile are
// consecutive logical blocks -> same XCD -> Ut re-reads hit that XCD's L2.
__global__ __launch_bounds__(256) void gemm_t1(
    const short* __restrict__ A,    // [1024][256] bf16 (u-projection)
    const short* __restrict__ Ut,   // [65536][256] bf16 (B^T layout)
    short* __restrict__ C)          // [1024][65536] bf16
{
  __shared__ short As[128 * 32];
  __shared__ short Bs[128 * 32];
  const int tid = threadIdx.x;
  const int wave = tid >> 6, lane = tid & 63;
  const int ln15 = lane & 15, quad = lane >> 4;
  const int h = blockIdx.x;                 // 4096 blocks, hw id
  const int l = (h & 7) * 512 + (h >> 3);   // bijective chunk swizzle (4096%8==0)
  const int m0 = (l & 7) * 128, n0 = (l >> 3) * 128;
  const int wm = (wave & 1) * 64, wn = (wave >> 1) * 64;
  const int q0 = tid,        r0 = q0 >> 2, s0 = (q0 & 3) ^ ((r0 >> 1) & 3);
  const int q1 = tid + 256,  r1 = q1 >> 2, s1 = (q1 & 3) ^ ((r1 >> 1) & 3);
  const int rdoff = ((quad ^ ((ln15 >> 1) & 3)) << 3);
  f32x4 acc[4][4] = {};
  for (int kt = 0; kt < ADIM; kt += 32) {
    __syncthreads();
    gload16(&A [(size_t)(m0 + r0) * ADIM + kt + s0 * 8], &As[q0 * 8]);
    gload16(&A [(size_t)(m0 + r1) * ADIM + kt + s1 * 8], &As[q1 * 8]);
    gload16(&Ut[(size_t)(n0 + r0) * ADIM + kt + s0 * 8], &Bs[q0 * 8]);
    gload16(&Ut[(size_t)(n0 + r1) * ADIM + kt + s1 * 8], &Bs[q1 * 8]);
    __syncthreads();
    bf16x8 af[4], bfr[4];
    #pragma unroll
    for (int r = 0; r < 4; ++r)  af[r]  = *(bf16x8*)&As[(wm + r * 16 + ln15) * 32 + rdoff];
    #pragma unroll
    for (int c2 = 0; c2 < 4; ++c2) bfr[c2] = *(bf16x8*)&Bs[(wn + c2 * 16 + ln15) * 32 + rdoff];
    #pragma unroll
    for (int r = 0; r < 4; ++r)
      #pragma unroll
      for (int c2 = 0; c2 < 4; ++c2)
        acc[r][c2] = MFMA_BF16(bfr[c2], af[r], acc[r][c2]);  // swapped: lane holds 4 consecutive n
  }
  #pragma unroll
  for (int r = 0; r < 4; ++r)
    #pragma unroll
    for (int c2 = 0; c2 < 4; ++c2) {
      int m = m0 + wm + r * 16 + ln15;
      int n = n0 + wn + c2 * 16 + quad * 4;
      ushort4 o;
      o.x = (unsigned short)f2bf(acc[r][c2][0]);
      o.y = (unsigned short)f2bf(acc[r][c2][1]);
      o.z = (unsigned short)f2bf(acc[r][c2][2]);
      o.w = (unsigned short)f2bf(acc[r][c2][3]);
      *(ushort4*)&C[(size_t)m * NSQ + n] = o;
    }
}

// ---------------- fused phases A+B per (b,i): t2 kept in LDS -----------------
// phase A: t2_i[j][d] = sum_c projv[b][j][c] * t1[b,i,d,c]   (two d-halves)
// phase B: S[b,i,j,k]  = sum_d t2_i[j][d] * projw[b][k][d]
// t2s LDS [128 j][256 d] bf16, 16B-slot XOR swizzle: slot' = slot ^ (j&7)
// (row stride 512B -> without swizzle phase-B reads would be 16-way conflicts).
__global__ __launch_bounds__(256) void fuse_ts(
    const short* __restrict__ t1,     // [1024][65536] bf16 (this type)
    const short* __restrict__ projv,  // [1024][256] bf16
    const short* __restrict__ projw,  // [1024][256] bf16
    float* __restrict__ out)          // [8][128][128][128] f32 (this type)
{
  __shared__ short As[128 * 32];
  __shared__ short Bs[128 * 32];
  __shared__ short t2s[128 * 256];    // 64 KB
  const int tid = threadIdx.x;
  const int wave = tid >> 6, lane = tid & 63;
  const int ln15 = lane & 15, quad = lane >> 4;
  const int i  = blockIdx.x;
  const int bl = blockIdx.y;
  const short* Bt = t1 + (size_t)(bl * N_TOK + i) * NSQ;   // [256 d][256 c]
  const short* Av = projv + (size_t)bl * N_TOK * ADIM;     // [128 j][256 c]
  const short* Bw = projw + (size_t)bl * N_TOK * ADIM;     // [128 k][256 d]
  float* ob = out + (size_t)(bl * N_TOK + i) * N_TOK * N_TOK;
  const int wm = (wave & 1) * 64, wn = (wave >> 1) * 64;
  const int q0 = tid,        r0 = q0 >> 2, s0 = (q0 & 3) ^ ((r0 >> 1) & 3);
  const int q1 = tid + 256,  r1 = q1 >> 2, s1 = (q1 & 3) ^ ((r1 >> 1) & 3);
  const int rdoff = ((quad ^ ((ln15 >> 1) & 3)) << 3);

  // ---- phase A: two d-halves of 128, each M=128(j) x N=128(d) x K=256(c)
  for (int dh = 0; dh < 2; ++dh) {
    f32x4 acc[4][4] = {};
    for (int ct = 0; ct < ADIM; ct += 32) {
      __syncthreads();
      gload16(&Av[(size_t)r0 * ADIM + ct + s0 * 8],              &As[q0 * 8]);
      gload16(&Av[(size_t)r1 * ADIM + ct + s1 * 8],              &As[q1 * 8]);
      gload16(&Bt[(size_t)(dh * 128 + r0) * ADIM + ct + s0 * 8], &Bs[q0 * 8]);
      gload16(&Bt[(size_t)(dh * 128 + r1) * ADIM + ct + s1 * 8], &Bs[q1 * 8]);
      __syncthreads();
      bf16x8 af[4], bfr[4];
      #pragma unroll
      for (int r = 0; r < 4; ++r)
        af[r]  = *(bf16x8*)&As[(wm + r * 16 + ln15) * 32 + rdoff];
      #pragma unroll
      for (int c2 = 0; c2 < 4; ++c2)
        bfr[c2] = *(bf16x8*)&Bs[(wn + c2 * 16 + ln15) * 32 + rdoff];
      #pragma unroll
      for (int r = 0; r < 4; ++r)
        #pragma unroll
        for (int c2 = 0; c2 < 4; ++c2)
          acc[r][c2] = MFMA_BF16(bfr[c2], af[r], acc[r][c2]);  // lane: 4 consecutive d
    }
    // write to t2s (swizzled); wave-private rows, no barrier needed here
    #pragma unroll
    for (int r = 0; r < 4; ++r)
      #pragma unroll
      for (int c2 = 0; c2 < 4; ++c2) {
        int j  = wm + r * 16 + ln15;
        int d  = dh * 128 + wn + c2 * 16 + quad * 4;
        int sp = (d >> 3) ^ (j & 7);
        ushort4 o;
        o.x = (unsigned short)f2bf(acc[r][c2][0]);
        o.y = (unsigned short)f2bf(acc[r][c2][1]);
        o.z = (unsigned short)f2bf(acc[r][c2][2]);
        o.w = (unsigned short)f2bf(acc[r][c2][3]);
        *(ushort4*)((char*)t2s + (size_t)j * 512 + sp * 16 + (quad & 1) * 8) = o;
      }
  }
  __syncthreads();   // t2s complete; also orders phase-B Bs staging vs phase-A reads

  // ---- phase B: M=128(j) x N=128(k) x K=256(d); A from t2s (LDS), B staged
  f32x4 acc2[4][4] = {};
  for (int dt = 0; dt < ADIM; dt += 32) {
    if (dt) __syncthreads();
    gload16(&Bw[(size_t)r0 * ADIM + dt + s0 * 8], &Bs[q0 * 8]);
    gload16(&Bw[(size_t)r1 * ADIM + dt + s1 * 8], &Bs[q1 * 8]);
    __syncthreads();
    bf16x8 a2[4], b2[4];
    #pragma unroll
    for (int fr = 0; fr < 4; ++fr) {
      int j  = wm + fr * 16 + ln15;
      int sp = ((dt >> 3) + quad) ^ (j & 7);
      a2[fr] = *(bf16x8*)((char*)t2s + (size_t)j * 512 + sp * 16);
    }
    #pragma unroll
    for (int fc = 0; fc < 4; ++fc)
      b2[fc] = *(bf16x8*)&Bs[(wn + fc * 16 + ln15) * 32 + rdoff];
    #pragma unroll
    for (int fr = 0; fr < 4; ++fr)
      #pragma unroll
      for (int fc = 0; fc < 4; ++fc)
        acc2[fr][fc] = MFMA_BF16(b2[fc], a2[fr], acc2[fr][fc]);  // lane: 4 consecutive k
  }
  #pragma unroll
  for (int fr = 0; fr < 4; ++fr)
    #pragma unroll
    for (int fc = 0; fc < 4; ++fc) {
      int j = wm + fr * 16 + ln15;
      int k = wn + fc * 16 + quad * 4;
      *(f32x4*)&ob[(size_t)j * N_TOK + k] = acc2[fr][fc];   // 16B store, full lines
    }
}

// ---------------- mask passthrough -----------------------------------------
__global__ void mask_kernel(const int* __restrict__ mask, float* __restrict__ out) {
  int idx = blockIdx.x * 256 + threadIdx.x;
  if (idx < BSZ * N_TOK) {
    int b = idx >> 7, i = idx & 127;
    out[idx] = (i == 0) ? 1.0f : (float)mask[b * 127 + i - 1];
  }
}

extern "C" void kernel_launch(void* const* d_in, const int* in_sizes, int n_in,
                              void* d_out, int out_size, void* d_ws, size_t ws_size,
                              hipStream_t stream)
{
  const float* x    = (const float*)d_in[0];
  const int*   mask = (const int*)d_in[2];
  ProjArgs pa;
  for (int p = 0; p < 7; ++p) {
    pa.W[p] = (const float*)d_in[3 + 2 * p];
    pa.b[p] = (const float*)d_in[4 + 2 * p];
  }
  UArgs ua;
  ua.U[0] = (const float*)d_in[17];
  ua.U[1] = (const float*)d_in[18];
  ua.U[2] = (const float*)d_in[19];
  const float* sentinel = (const float*)d_in[20];

  // workspace: proj 4MB | Ut 3x32MB=96MB | t1 128MB (reused per type) = 228MB
  short* proj = (short*)d_ws;
  const size_t ut_off = 4u << 20;
  const size_t t1_off = ut_off + 3 * ((size_t)NSQ * ADIM * 2);    // +96MB
  short* UtAll = (short*)((char*)d_ws + ut_off);
  short* t1    = (short*)((char*)d_ws + t1_off);

  proj_kernel<<<dim3(128, 7), 256, 0, stream>>>(x, sentinel, pa, proj);
  permU_all<<<dim3(256, 4, 12), 256, 0, stream>>>(ua, UtAll);

  const int u_idx[3] = {0, 2, 4};
  const int v_idx[3] = {1, 3, 6};
  const int w_idx[3] = {1, 2, 5};
  float* outp = (float*)d_out;

  for (int sc = 0; sc < 3; ++sc) {
    gemm_t1<<<dim3(4096), 256, 0, stream>>>(
        proj + (size_t)u_idx[sc] * 1024 * ADIM,
        UtAll + (size_t)sc * NSQ * ADIM, t1);
    fuse_ts<<<dim3(128, 8), 256, 0, stream>>>(
        t1,
        proj + (size_t)v_idx[sc] * 1024 * ADIM,
        proj + (size_t)w_idx[sc] * 1024 * ADIM,
        outp + (size_t)sc * BSZ * N_TOK * N_TOK * N_TOK);
  }
  mask_kernel<<<dim3(4), 256, 0, stream>>>(
      mask, outp + (size_t)3 * BSZ * N_TOK * N_TOK * N_TOK);
}